// Round 3
// baseline (355.036 us; speedup 1.0000x reference)
//
#include <hip/hip_runtime.h>

// out[f, i] = dot(kernel[f], x[i]) + dot(enc[i % P], x[i])
// x: [M=372000, K=125] f32, enc: [P=23250, 125] f32, w: [125, 64] f32 (k-major),
// out flat: [F=64, M] f32 (reference reshape is a pure reinterpret).
//
// Round 3: latency-bound fix. BM=64 + 8 blocks/CU (32 waves, 2x occupancy),
// LDS-transpose epilogue so every store instruction writes 8 f-rows x 128 B
// full aligned HBM lines (kills the 1.71x write amplification seen in r2).

#define P_    23250u
#define K_    125
#define F_    64
#define M_TOT 372000
#define BM    64
#define NBLK  ((M_TOT + BM - 1) / BM)   // 5813
#define TSTR  68                        // transpose LDS stride in floats (272 B, 16B-aligned)

typedef __bf16 bf16;
typedef __bf16 bf16x4 __attribute__((ext_vector_type(4)));
typedef __bf16 bf16x8 __attribute__((ext_vector_type(8)));
typedef float  f32x4  __attribute__((ext_vector_type(4)));
typedef float  f32x4u __attribute__((ext_vector_type(4), aligned(4)));  // 4B-aligned vec load

// ---- prep: per-(lane,wave) kernel fragments, linear in d_ws ----------------
// thread tid -> f = (tid>>6)*16 + (tid&15), kg = (tid>>4)&3
// wfrag[tid*32 + ks*8 + j] = bf16(w[(ks*32+kg*8+j)*64 + f]), 0-pad k>=125
__global__ __launch_bounds__(256, 1)
void prep_wfrag(const float* __restrict__ w, bf16* __restrict__ wfrag)
{
    const int tid = threadIdx.x;
    const int f  = ((tid >> 6) << 4) | (tid & 15);
    const int kg = (tid >> 4) & 3;
    #pragma unroll
    for (int ks = 0; ks < 4; ++ks) {
        bf16x8 fr;
        #pragma unroll
        for (int j = 0; j < 8; ++j) {
            const int k = ks * 32 + kg * 8 + j;
            fr[j] = (bf16)((k < K_) ? w[k * F_ + f] : 0.0f);
        }
        *(bf16x8*)(wfrag + tid * 32 + ks * 8) = fr;
    }
}

__global__ __launch_bounds__(256, 8)
void eegconv_kernel(const float* __restrict__ x,
                    const float* __restrict__ enc,
                    const bf16* __restrict__ wfrag,
                    float* __restrict__ out)
{
    // union: staging tile (64 rows x 128 bf16 = 16384 B) / transpose (64 f x 68 f32 = 17408 B)
    __shared__ __attribute__((aligned(16))) char raw[F_ * TSTR * 4];
    __shared__ __attribute__((aligned(16))) float srow[BM];

    const int tid  = threadIdx.x;
    const int lane = tid & 63;
    const int wv   = tid >> 6;       // wave -> f-tile [16wv, 16wv+16)
    const int fl   = lane & 15;
    const int kg   = lane >> 4;      // 0..3
    const int r0   = blockIdx.x * BM;

    // ---- kernel fragments from workspace (L2-hot, thread-linear) ----
    bf16x8 kf[4];
    {
        const bf16x8* wf = (const bf16x8*)(wfrag + tid * 32);
        #pragma unroll
        for (int ks = 0; ks < 4; ++ks) kf[ks] = wf[ks];
    }

    // ---- Stage x tile (bf16, swizzled) + srow = dot(enc_row, x_row) ----
    bf16* xt = (bf16*)raw;
    {
        const int row = tid >> 2;            // 4 threads per row
        const int t4  = tid & 3;
        int gi = r0 + row;
        if (gi >= M_TOT) gi = 0;             // redirect invalid rows (stores guarded later)
        const float* xr = x   + (size_t)gi * K_;
        const float* er = enc + (size_t)((unsigned)gi % P_) * K_;
        char* lbase = (char*)xt + row * 256;
        const int sw = (row & 7) << 4;       // bank-conflict swizzle
        float part = 0.0f;

        #pragma unroll
        for (int u = 0; u < 8; ++u) {
            const int c = u * 4 + t4;        // 0..31
            f32x4 xv, ev;
            if (c < 31) {                    // full float4 (rows are 4B-aligned)
                xv = (f32x4)*(const f32x4u*)(xr + c * 4);
                ev = (f32x4)*(const f32x4u*)(er + c * 4);
            } else {                         // tail: only col 124 valid
                xv = f32x4{xr[124], 0.f, 0.f, 0.f};
                ev = f32x4{er[124], 0.f, 0.f, 0.f};
            }
            part += ev.x * xv.x + ev.y * xv.y + ev.z * xv.z + ev.w * xv.w;
            bf16x4 bv;
            bv[0] = (bf16)xv.x; bv[1] = (bf16)xv.y; bv[2] = (bf16)xv.z; bv[3] = (bf16)xv.w;
            *(bf16x4*)(lbase + ((c * 8) ^ sw)) = bv;
        }
        part += __shfl_xor(part, 1);
        part += __shfl_xor(part, 2);
        if (t4 == 0) srow[row] = part;
    }
    __syncthreads();

    // ---- MFMA: D[i][f], A = x rows (LDS), B = kernel frags ----
    f32x4 acc[4];
    #pragma unroll
    for (int t = 0; t < 4; ++t) acc[t] = f32x4{0.f, 0.f, 0.f, 0.f};

    #pragma unroll
    for (int t = 0; t < 4; ++t) {
        const int il = t * 16 + fl;
        const char* rbase = (const char*)xt + il * 256;
        const int sw = (il & 7) << 4;
        #pragma unroll
        for (int ks = 0; ks < 4; ++ks) {
            const bf16x8 av = *(const bf16x8*)(rbase + ((ks * 64 + kg * 16) ^ sw));
            acc[t] = __builtin_amdgcn_mfma_f32_16x16x32_bf16(av, kf[ks], acc[t], 0, 0, 0);
        }
    }
    __syncthreads();   // staging buffer dead, safe to overwrite

    // ---- acc -> LDS transpose buffer [f][TSTR] ----
    float* tr = (float*)raw;
    {
        const int f = wv * 16 + fl;
        #pragma unroll
        for (int t = 0; t < 4; ++t) {
            const int i0 = t * 16 + kg * 4;          // lane's 4 consecutive i
            *(f32x4*)(tr + f * TSTR + i0) = acc[t];
        }
    }
    __syncthreads();

    // ---- full-line stores: per instr, 8 f-rows x 128 B contiguous aligned ----
    {
        const int m8 = tid & 7;
        const int fg = tid >> 3;                     // 0..31
        #pragma unroll
        for (int p = 0; p < 2; ++p) {
            const int f = p * 32 + fg;
            const float* src = tr + f * TSTR;
            const size_t ob = (size_t)f * M_TOT + r0;
            #pragma unroll
            for (int h = 0; h < 2; ++h) {
                const int ii = h * 32 + m8 * 4;
                if (r0 + ii < M_TOT) {               // guard (last block: 32 valid rows)
                    f32x4 v  = *(const f32x4*)(src + ii);
                    const f32x4 sv = *(const f32x4*)(srow + ii);
                    v.x += sv.x; v.y += sv.y; v.z += sv.z; v.w += sv.w;
                    *(f32x4*)(out + ob + ii) = v;
                }
            }
        }
    }
}

extern "C" void kernel_launch(void* const* d_in, const int* in_sizes, int n_in,
                              void* d_out, int out_size, void* d_ws, size_t ws_size,
                              hipStream_t stream)
{
    const float* x   = (const float*)d_in[0];
    const float* enc = (const float*)d_in[1];
    const float* w   = (const float*)d_in[2];
    float* out = (float*)d_out;
    bf16* wfrag = (bf16*)d_ws;                 // 16 KB
    prep_wfrag<<<1, 256, 0, stream>>>(w, wfrag);
    eegconv_kernel<<<NBLK, 256, 0, stream>>>(x, enc, wfrag, out);
}

// Round 4
// 325.697 us; speedup vs baseline: 1.0901x; 1.0901x over previous
//
#include <hip/hip_runtime.h>

// out[f, i] = dot(kernel[f], x[i]) + dot(enc[i % P], x[i])
// x: [M=372000, K=125] f32, enc: [P=23250, 125] f32, w: [125, 64] f32 (k-major),
// out flat: [F=64, M] f32 (reference reshape is a pure reinterpret).
//
// Round 4: (a) launch_bounds(256,4) -> 128 VGPR budget, kills the scratch
// spill that inflated WRITE_SIZE to 250 MB in r3; (b) grid reordered to
// (p-tile, n) with bijective XCD swizzle so the 16 batches sharing an enc
// tile run consecutively on one XCD (enc served from L2, not L3/HBM);
// (c) full-line transpose epilogue kept, scalar-guarded tail tile.

#define P_    23250
#define K_    125
#define F_    64
#define N_    16
#define M_TOT 372000
#define NPT   364              // ceil(P_/64); last tile has 18 valid rows
#define NWG   (NPT * N_)       // 5824 = 8 * 728  (divisible by 8 -> bijective swizzle)
#define CPX   (NWG / 8)        // 728 blocks per XCD
#define TSTR  68               // transpose LDS stride in floats (272 B)

typedef __bf16 bf16;
typedef __bf16 bf16x4 __attribute__((ext_vector_type(4)));
typedef __bf16 bf16x8 __attribute__((ext_vector_type(8)));
typedef float  f32x4  __attribute__((ext_vector_type(4)));
typedef float  f32x4u __attribute__((ext_vector_type(4), aligned(4)));  // 4B-aligned vec ld/st

// ---- prep: per-(lane,wave) kernel fragments, thread-linear in d_ws ---------
// wfrag[tid*32 + ks*8 + j] = bf16(w[(ks*32+kg*8+j)*64 + f]), 0-pad k>=125
__global__ __launch_bounds__(256, 1)
void prep_wfrag(const float* __restrict__ w, bf16* __restrict__ wfrag)
{
    const int tid = threadIdx.x;
    const int f  = ((tid >> 6) << 4) | (tid & 15);
    const int kg = (tid >> 4) & 3;
    #pragma unroll
    for (int ks = 0; ks < 4; ++ks) {
        bf16x8 fr;
        #pragma unroll
        for (int j = 0; j < 8; ++j) {
            const int k = ks * 32 + kg * 8 + j;
            fr[j] = (bf16)((k < K_) ? w[k * F_ + f] : 0.0f);
        }
        *(bf16x8*)(wfrag + tid * 32 + ks * 8) = fr;
    }
}

__global__ __launch_bounds__(256, 4)
void eegconv_kernel(const float* __restrict__ x,
                    const float* __restrict__ enc,
                    const bf16* __restrict__ wfrag,
                    float* __restrict__ out)
{
    // union: staging tile (64 x 128 bf16 = 16 KB) / transpose (64 x 68 f32 = 17.4 KB)
    __shared__ __attribute__((aligned(16))) char raw[F_ * TSTR * 4];
    __shared__ __attribute__((aligned(16))) float srow[64];

    const int tid  = threadIdx.x;
    const int lane = tid & 63;
    const int wv   = tid >> 6;       // wave -> f-tile [16wv, 16wv+16)
    const int fl   = lane & 15;
    const int kg   = lane >> 4;      // 0..3

    // ---- (p-tile, n) decomposition with XCD-chunked bijective swizzle ----
    // consecutive dispatch ids round-robin XCDs; this gives XCD k the
    // contiguous wgid range [k*CPX, (k+1)*CPX) in dispatch order, so the
    // 16 n-blocks of one p-tile run back-to-back on one XCD (enc L2-hot).
    const int wgid  = (blockIdx.x & 7) * CPX + (blockIdx.x >> 3);
    const int ptile = wgid >> 4;
    const int n     = wgid & 15;
    const int p0    = ptile * 64;

    // ---- kernel fragments from workspace (thread-linear, L2-hot) ----
    bf16x8 kf[4];
    {
        const bf16x8* wf = (const bf16x8*)(wfrag + tid * 32);
        #pragma unroll
        for (int ks = 0; ks < 4; ++ks) kf[ks] = wf[ks];
    }

    // ---- Stage x tile (bf16, swizzled) + srow = dot(enc_row, x_row) ----
    bf16* xt = (bf16*)raw;
    {
        const int row = tid >> 2;            // 4 threads per row
        const int t4  = tid & 3;
        const int p   = p0 + row;
        const int pe  = (p < P_) ? p : 0;    // redirect invalid rows (stores guarded)
        const float* xr = x   + (size_t)(n * P_ + pe) * K_;
        const float* er = enc + (size_t)pe * K_;
        char* lbase = (char*)xt + row * 256;
        const int sw = (row & 7) << 4;       // bank-conflict swizzle
        float part = 0.0f;

        #pragma unroll
        for (int u = 0; u < 8; ++u) {
            const int c = u * 4 + t4;        // 0..31
            f32x4 xv, ev;
            if (c < 31) {                    // full float4 (rows 4B-aligned)
                xv = (f32x4)*(const f32x4u*)(xr + c * 4);
                ev = (f32x4)*(const f32x4u*)(er + c * 4);
            } else {                         // tail: only col 124 valid
                xv = f32x4{xr[124], 0.f, 0.f, 0.f};
                ev = f32x4{er[124], 0.f, 0.f, 0.f};
            }
            part += ev.x * xv.x + ev.y * xv.y + ev.z * xv.z + ev.w * xv.w;
            bf16x4 bv;
            bv[0] = (bf16)xv.x; bv[1] = (bf16)xv.y; bv[2] = (bf16)xv.z; bv[3] = (bf16)xv.w;
            *(bf16x4*)(lbase + ((c * 8) ^ sw)) = bv;
        }
        part += __shfl_xor(part, 1);
        part += __shfl_xor(part, 2);
        if (t4 == 0) srow[row] = part;
    }
    __syncthreads();

    // ---- MFMA: D[i][f], A = x rows (LDS), B = kernel frags ----
    f32x4 acc[4];
    #pragma unroll
    for (int t = 0; t < 4; ++t) acc[t] = f32x4{0.f, 0.f, 0.f, 0.f};

    #pragma unroll
    for (int t = 0; t < 4; ++t) {
        const int il = t * 16 + fl;
        const char* rbase = (const char*)xt + il * 256;
        const int sw = (il & 7) << 4;
        #pragma unroll
        for (int ks = 0; ks < 4; ++ks) {
            const bf16x8 av = *(const bf16x8*)(rbase + ((ks * 64 + kg * 16) ^ sw));
            acc[t] = __builtin_amdgcn_mfma_f32_16x16x32_bf16(av, kf[ks], acc[t], 0, 0, 0);
        }
    }
    __syncthreads();   // staging buffer dead, safe to overwrite

    // ---- acc -> LDS transpose buffer [f][TSTR] ----
    float* tr = (float*)raw;
    {
        const int f = wv * 16 + fl;
        #pragma unroll
        for (int t = 0; t < 4; ++t) {
            const int i0 = t * 16 + kg * 4;          // lane's 4 consecutive i
            *(f32x4*)(tr + f * TSTR + i0) = acc[t];
        }
    }
    __syncthreads();

    // ---- stores: per instr, 8 f-rows x 128 B contiguous (full HBM lines) ----
    {
        const int m8 = tid & 7;
        const int fg = tid >> 3;                     // 0..31
        const bool full = (p0 + 64 <= P_);           // 363/364 tiles
        #pragma unroll
        for (int pp = 0; pp < 2; ++pp) {
            const int f = pp * 32 + fg;
            const float* src = tr + f * TSTR;
            float* ob = out + (size_t)f * M_TOT + (size_t)n * P_ + p0;
            #pragma unroll
            for (int h = 0; h < 2; ++h) {
                const int ii = h * 32 + m8 * 4;
                f32x4 v  = *(const f32x4*)(src + ii);
                const f32x4 sv = *(const f32x4*)(srow + ii);
                v.x += sv.x; v.y += sv.y; v.z += sv.z; v.w += sv.w;
                if (full) {
                    *(f32x4u*)(ob + ii) = v;         // 4B-aligned vec store (n*P_ shifts 8B)
                } else {                             // tail tile: 18 valid rows
                    #pragma unroll
                    for (int e = 0; e < 4; ++e)
                        if (p0 + ii + e < P_) ob[ii + e] = v[e];
                }
            }
        }
    }
}

extern "C" void kernel_launch(void* const* d_in, const int* in_sizes, int n_in,
                              void* d_out, int out_size, void* d_ws, size_t ws_size,
                              hipStream_t stream)
{
    const float* x   = (const float*)d_in[0];
    const float* enc = (const float*)d_in[1];
    const float* w   = (const float*)d_in[2];
    float* out = (float*)d_out;
    bf16* wfrag = (bf16*)d_ws;                 // 16 KB
    prep_wfrag<<<1, 256, 0, stream>>>(w, wfrag);
    eegconv_kernel<<<NWG, 256, 0, stream>>>(x, enc, wfrag, out);
}

// Round 5
// 316.051 us; speedup vs baseline: 1.1233x; 1.0305x over previous
//
#include <hip/hip_runtime.h>

// out[f, i] = dot(kernel[f], x[i]) + dot(enc[i % P], x[i])
// x: [16*23250, 125] f32, enc: [23250, 125] f32, w: [125, 64] f32,
// out flat: [64, 372000] f32 (reference reshape is a pure reinterpret).
//
// Round 5: latency-exposure fix. Block owns (ptile, npair) = 2 jobs sharing
// the same enc rows: enc loaded ONCE into registers and reused; x loads for
// job1 issued BEFORE job0's MFMA+stores (T14 issue-early); double-buffered
// bf16 LDS tile; direct acc stores (no transpose — r3's write amplification
// was spill, not store pattern). launch_bounds(256,4) = 128 VGPR budget.

#define P_    23250
#define K_    125
#define F_    64
#define M_TOT 372000
#define NPT   364              // ceil(P/64); last tile has 18 valid rows
#define NWG   (NPT * 8)        // 2912 = 8 * 364 blocks; block = (ptile, npair)
#define CPX   (NWG / 8)        // 364 blocks per XCD chunk

typedef __bf16 bf16;
typedef __bf16 bf16x4 __attribute__((ext_vector_type(4)));
typedef __bf16 bf16x8 __attribute__((ext_vector_type(8)));
typedef float  f32x4  __attribute__((ext_vector_type(4)));
typedef float  f32x4u __attribute__((ext_vector_type(4), aligned(4)));  // 4B-aligned vec ld/st

// ---- prep: per-(lane,wave) kernel fragments, thread-linear in d_ws ---------
__global__ __launch_bounds__(256, 1)
void prep_wfrag(const float* __restrict__ w, bf16* __restrict__ wfrag)
{
    const int tid = threadIdx.x;
    const int f  = ((tid >> 6) << 4) | (tid & 15);
    const int kg = (tid >> 4) & 3;
    #pragma unroll
    for (int ks = 0; ks < 4; ++ks) {
        bf16x8 fr;
        #pragma unroll
        for (int j = 0; j < 8; ++j) {
            const int k = ks * 32 + kg * 8 + j;
            fr[j] = (bf16)((k < K_) ? w[k * F_ + f] : 0.0f);
        }
        *(bf16x8*)(wfrag + tid * 32 + ks * 8) = fr;
    }
}

__global__ __launch_bounds__(256, 4)
void eegconv_kernel(const float* __restrict__ x,
                    const float* __restrict__ enc,
                    const bf16* __restrict__ wfrag,
                    float* __restrict__ out)
{
    __shared__ __attribute__((aligned(16))) bf16  xt[2][64 * 128];  // swizzled, 2x16 KB
    __shared__ __attribute__((aligned(16))) float srow[2][64];

    const int tid  = threadIdx.x;
    const int lane = tid & 63;
    const int wv   = tid >> 6;       // wave -> f-tile [16wv, 16wv+16)
    const int fl   = lane & 15;
    const int kg   = lane >> 4;      // 0..3

    // XCD-chunked bijective swizzle; 8 sibling blocks (same ptile) adjacent
    // on one XCD -> enc tile L2-hot across its 16 n-consumers.
    const int wgid  = (blockIdx.x & 7) * CPX + (blockIdx.x >> 3);
    const int ptile = wgid >> 3;
    const int npair = wgid & 7;
    const int p0    = ptile * 64;
    const int n0    = npair * 2;

    // ---- kernel fragments (thread-linear, L2-hot) ----
    bf16x8 kf[4];
    {
        const bf16x8* wf = (const bf16x8*)(wfrag + tid * 32);
        #pragma unroll
        for (int ks = 0; ks < 4; ++ks) kf[ks] = wf[ks];
    }

    const int row = tid >> 2;            // 4 threads per row
    const int t4  = tid & 3;
    const int p   = p0 + row;
    const int pe  = (p < P_) ? p : (P_ - 1);   // redirect invalid rows (stores guarded)
    const float* er  = enc + (size_t)pe * K_;
    const float* xr0 = x + (size_t)(n0 * P_ + pe) * K_;
    const float* xr1 = x + (size_t)((n0 + 1) * P_ + pe) * K_;
    char* lb0 = (char*)&xt[0][0] + row * 256;
    char* lb1 = (char*)&xt[1][0] + row * 256;
    const int sw = (row & 7) << 4;       // LDS bank swizzle

    // ---- prologue: enc rows (persist across both jobs) + x(job0) ----
    f32x4 ev[8], xv[8];
    #pragma unroll
    for (int u = 0; u < 8; ++u) {
        const int c = u * 4 + t4;
        if (c < 31) ev[u] = (f32x4)*(const f32x4u*)(er + c * 4);
        else        ev[u] = f32x4{er[124], 0.f, 0.f, 0.f};
    }
    #pragma unroll
    for (int u = 0; u < 8; ++u) {
        const int c = u * 4 + t4;
        if (c < 31) xv[u] = (f32x4)*(const f32x4u*)(xr0 + c * 4);
        else        xv[u] = f32x4{xr0[124], 0.f, 0.f, 0.f};
    }
    // cvt + srow + stage job0
    {
        float part = 0.f;
        #pragma unroll
        for (int u = 0; u < 8; ++u) {
            const int c = u * 4 + t4;
            part += ev[u].x * xv[u].x + ev[u].y * xv[u].y
                  + ev[u].z * xv[u].z + ev[u].w * xv[u].w;
            bf16x4 bv;
            bv[0] = (bf16)xv[u].x; bv[1] = (bf16)xv[u].y;
            bv[2] = (bf16)xv[u].z; bv[3] = (bf16)xv[u].w;
            *(bf16x4*)(lb0 + ((c * 8) ^ sw)) = bv;
        }
        part += __shfl_xor(part, 1);
        part += __shfl_xor(part, 2);
        if (t4 == 0) srow[0][row] = part;
    }
    __syncthreads();

    // ---- issue x(job1) EARLY: in flight across job0's MFMA + stores ----
    #pragma unroll
    for (int u = 0; u < 8; ++u) {
        const int c = u * 4 + t4;
        if (c < 31) xv[u] = (f32x4)*(const f32x4u*)(xr1 + c * 4);
        else        xv[u] = f32x4{xr1[124], 0.f, 0.f, 0.f};
    }

    const size_t fM   = (size_t)(wv * 16 + fl) * (size_t)M_TOT;
    const bool   full = (p0 + 64 <= P_);

    // ---- job0: MFMA + direct stores ----
    {
        f32x4 acc[4];
        #pragma unroll
        for (int t = 0; t < 4; ++t) acc[t] = f32x4{0.f, 0.f, 0.f, 0.f};
        #pragma unroll
        for (int t = 0; t < 4; ++t) {
            const int il = t * 16 + fl;
            const char* rb = (const char*)&xt[0][0] + il * 256;
            const int s2 = (il & 7) << 4;
            #pragma unroll
            for (int ks = 0; ks < 4; ++ks) {
                const bf16x8 av = *(const bf16x8*)(rb + ((ks * 64 + kg * 16) ^ s2));
                acc[t] = __builtin_amdgcn_mfma_f32_16x16x32_bf16(av, kf[ks], acc[t], 0, 0, 0);
            }
        }
        float* ob = out + fM + (size_t)n0 * P_ + p0;
        #pragma unroll
        for (int t = 0; t < 4; ++t) {
            const int i0 = t * 16 + kg * 4;
            const f32x4 sv = *(const f32x4*)(&srow[0][i0]);
            f32x4 v;
            v.x = acc[t][0] + sv.x; v.y = acc[t][1] + sv.y;
            v.z = acc[t][2] + sv.z; v.w = acc[t][3] + sv.w;
            if (full) {
                *(f32x4u*)(ob + i0) = v;
            } else {
                #pragma unroll
                for (int e = 0; e < 4; ++e)
                    if (p0 + i0 + e < P_) ob[i0 + e] = v[e];
            }
        }
    }

    // ---- stage job1 (consumes early loads; enc regs reused) ----
    {
        float part = 0.f;
        #pragma unroll
        for (int u = 0; u < 8; ++u) {
            const int c = u * 4 + t4;
            part += ev[u].x * xv[u].x + ev[u].y * xv[u].y
                  + ev[u].z * xv[u].z + ev[u].w * xv[u].w;
            bf16x4 bv;
            bv[0] = (bf16)xv[u].x; bv[1] = (bf16)xv[u].y;
            bv[2] = (bf16)xv[u].z; bv[3] = (bf16)xv[u].w;
            *(bf16x4*)(lb1 + ((c * 8) ^ sw)) = bv;
        }
        part += __shfl_xor(part, 1);
        part += __shfl_xor(part, 2);
        if (t4 == 0) srow[1][row] = part;
    }
    __syncthreads();

    // ---- job1: MFMA + direct stores ----
    {
        f32x4 acc[4];
        #pragma unroll
        for (int t = 0; t < 4; ++t) acc[t] = f32x4{0.f, 0.f, 0.f, 0.f};
        #pragma unroll
        for (int t = 0; t < 4; ++t) {
            const int il = t * 16 + fl;
            const char* rb = (const char*)&xt[1][0] + il * 256;
            const int s2 = (il & 7) << 4;
            #pragma unroll
            for (int ks = 0; ks < 4; ++ks) {
                const bf16x8 av = *(const bf16x8*)(rb + ((ks * 64 + kg * 16) ^ s2));
                acc[t] = __builtin_amdgcn_mfma_f32_16x16x32_bf16(av, kf[ks], acc[t], 0, 0, 0);
            }
        }
        float* ob = out + fM + (size_t)(n0 + 1) * P_ + p0;
        #pragma unroll
        for (int t = 0; t < 4; ++t) {
            const int i0 = t * 16 + kg * 4;
            const f32x4 sv = *(const f32x4*)(&srow[1][i0]);
            f32x4 v;
            v.x = acc[t][0] + sv.x; v.y = acc[t][1] + sv.y;
            v.z = acc[t][2] + sv.z; v.w = acc[t][3] + sv.w;
            if (full) {
                *(f32x4u*)(ob + i0) = v;
            } else {
                #pragma unroll
                for (int e = 0; e < 4; ++e)
                    if (p0 + i0 + e < P_) ob[i0 + e] = v[e];
            }
        }
    }
}

extern "C" void kernel_launch(void* const* d_in, const int* in_sizes, int n_in,
                              void* d_out, int out_size, void* d_ws, size_t ws_size,
                              hipStream_t stream)
{
    const float* x   = (const float*)d_in[0];
    const float* enc = (const float*)d_in[1];
    const float* w   = (const float*)d_in[2];
    float* out = (float*)d_out;
    bf16* wfrag = (bf16*)d_ws;                 // 16 KB
    prep_wfrag<<<1, 256, 0, stream>>>(w, wfrag);
    eegconv_kernel<<<NWG, 256, 0, stream>>>(x, enc, wfrag, out);
}